// Round 7
// baseline (85.726 us; speedup 1.0000x reference)
//
#include <hip/hip_runtime.h>
#include <stdint.h>

#define BATCH 128
#define HH 512
#define WW 512
#define BAND 64
#define NB (HH / BAND) /* 8 bands per batch */
#define HALO 3
#define PITCH 10 /* u64 per LDS row: 8 data + 2 pad */
#define MAGIC 0x5F3C9D21u

// ---- bit-domain helpers (layout: word w = h*4+k of a row; bit l <-> col 256h+4l+k) ----
__device__ __forceinline__ uint32_t popc8(const uint64_t* R) {
    uint32_t s = 0;
#pragma unroll
    for (int w = 0; w < 8; ++w) s += (uint32_t)__popcll(R[w]);
    return s;
}

// S(col p) = R(col p+sh), sh in 1..3 (compile-time).
__device__ __forceinline__ void shiftdn(const uint64_t* R, const int sh, uint64_t* S) {
#pragma unroll
    for (int t8 = 0; t8 < 2; ++t8)
#pragma unroll
        for (int k = 0; k < 4; ++k) {
            int kc = k + sh;
            if (kc < 4) {
                S[t8 * 4 + k] = R[t8 * 4 + kc];
            } else {
                uint64_t x = R[t8 * 4 + kc - 4] >> 1;
                if (t8 == 0) x |= R[4 + kc - 4] << 63;
                S[t8 * 4 + k] = x;
            }
        }
}

// Pair stats for column offset c != 0 (compile-time) between a-row A and b-row B.
__device__ __forceinline__ void procC(const uint64_t* A, const uint64_t* B, const int c,
                                      uint32_t* acc) {
    const int sh = c > 0 ? c : -c;
    uint64_t S[8];
    uint32_t oa = 0, ob = 0, on = 0;
    if (c > 0) {
        shiftdn(B, sh, S);
#pragma unroll
        for (int w = 0; w < 8; ++w) {
            uint64_t a = A[w];
            uint64_t am = ((w >> 2) == 1 && (w & 3) >= 4 - sh) ? (a & ~(1ull << 63)) : a;
            oa += (uint32_t)__popcll(am);
            ob += (uint32_t)__popcll(S[w]);
            on += (uint32_t)__popcll(a & S[w]);
        }
    } else {
        shiftdn(A, sh, S);
#pragma unroll
        for (int w = 0; w < 8; ++w) {
            uint64_t bb = B[w];
            uint64_t bm = ((w >> 2) == 1 && (w & 3) >= 4 - sh) ? (bb & ~(1ull << 63)) : bb;
            oa += (uint32_t)__popcll(S[w]);
            ob += (uint32_t)__popcll(bm);
            on += (uint32_t)__popcll(S[w] & bb);
        }
    }
    acc[0] += oa; acc[1] += ob; acc[2] += on;
}

__device__ __forceinline__ void proc0(const uint64_t* A, const uint64_t* B,
                                      uint32_t rpA, uint32_t rpB, uint32_t* acc) {
    uint32_t on = 0;
#pragma unroll
    for (int w = 0; w < 8; ++w) on += (uint32_t)__popcll(A[w] & B[w]);
    acc[0] += rpA; acc[1] += rpB; acc[2] += on;
}

__device__ __forceinline__ void loadrow(const uint64_t* lds, int y, uint64_t* R) {
#pragma unroll
    for (int i = 0; i < 4; ++i)
        *(ulonglong2*)&R[2 * i] = *(const ulonglong2*)&lds[y * PITCH + 2 * i];
}

// task id: row = id>>1, half = id&1
__device__ __forceinline__ float4 ldtask(const float* base, int y0, int id, int lane) {
    int row = id >> 1, half = id & 1;
    return *(const float4*)(base + (size_t)(y0 + row) * WW + half * 256 + lane * 4);
}

__device__ __forceinline__ void balstore(uint64_t* lds, int id, float4 v, int lane) {
    uint64_t m0 = __ballot(v.x < 0.f);
    uint64_t m1 = __ballot(v.y < 0.f);
    uint64_t m2 = __ballot(v.z < 0.f);
    uint64_t m3 = __ballot(v.w < 0.f);
    if (lane == 0) {
        int row = id >> 1, half = id & 1;
        uint64_t* p = &lds[row * PITCH + half * 4];
        ulonglong2 s0, s1;
        s0.x = m0; s0.y = m1; s1.x = m2; s1.y = m3;
        *(ulonglong2*)&p[0] = s0;
        *(ulonglong2*)&p[2] = s1;
    }
}

// Single fused kernel: ballot-pack band (+halo) into LDS, popcount all 12 offsets,
// write per-block partials; band-0 block of each batch finalizes via flag handshake.
// part[blk*36 + j*3 + q], flags[blk] (MAGIC protocol, self-resetting to 0).
__global__ __launch_bounds__(256, 4) void glcm_fused(const float* __restrict__ img,
                                                     uint32_t* __restrict__ part,
                                                     uint32_t* __restrict__ flags,
                                                     float* __restrict__ out) {
    __shared__ uint64_t lds[(BAND + HALO) * PITCH];
    int blk = (int)blockIdx.x;
    int band = blk & (NB - 1);
    int b = blk >> 3;
    int y0 = band * BAND;
    int t = (int)threadIdx.x, lane = t & 63, wv = t >> 6;
    const float* base = img + (size_t)b * HH * WW;

    int nrows = min(BAND + HALO, HH - y0);
    int ntasks = nrows * 2; /* half-rows */

    // ---- staging: pipelined ballot-pack (tasks strided by 4 waves) ----
    int id = wv;
    for (; id + 12 < ntasks; id += 16) {
        float4 v0 = ldtask(base, y0, id, lane);
        float4 v1 = ldtask(base, y0, id + 4, lane);
        float4 v2 = ldtask(base, y0, id + 8, lane);
        float4 v3 = ldtask(base, y0, id + 12, lane);
        balstore(lds, id, v0, lane);
        balstore(lds, id + 4, v1, lane);
        balstore(lds, id + 8, v2, lane);
        balstore(lds, id + 12, v3, lane);
    }
    for (; id < ntasks; id += 4) {
        float4 v = ldtask(base, y0, id, lane);
        balstore(lds, id, v, lane);
    }
    __syncthreads();

    // ---- compute: wave wv = offset group, lane = a-row within band ----
    uint32_t acc[3][3];
#pragma unroll
    for (int o = 0; o < 3; ++o) { acc[o][0] = 0; acc[o][1] = 0; acc[o][2] = 0; }

    int r = lane;
    uint64_t A[8];
    loadrow(lds, r, A);

    if (wv == 0) {
        procC(A, A, 1, acc[0]); /* (0,1) -> j0 */
        procC(A, A, 2, acc[1]); /* (0,2) -> j4 */
        procC(A, A, 3, acc[2]); /* (0,3) -> j8 */
    } else if (wv == 1) {
        if (y0 + r + 1 < HH) {
            uint64_t B[8];
            loadrow(lds, r + 1, B);
            uint32_t rpA = popc8(A), rpB = popc8(B);
            procC(A, B, 1, acc[0]);        /* (1, 1) -> j1 */
            proc0(A, B, rpA, rpB, acc[1]); /* (1, 0) -> j2 */
            procC(A, B, -1, acc[2]);       /* (1,-1) -> j3 */
        }
    } else if (wv == 2) {
        if (y0 + r + 2 < HH) {
            uint64_t B[8];
            loadrow(lds, r + 2, B);
            uint32_t rpA = popc8(A), rpB = popc8(B);
            procC(A, B, 2, acc[0]);        /* (2, 2) -> j5 */
            proc0(A, B, rpA, rpB, acc[1]); /* (2, 0) -> j6 */
            procC(A, B, -2, acc[2]);       /* (2,-2) -> j7 */
        }
    } else {
        if (y0 + r + 3 < HH) {
            uint64_t B[8];
            loadrow(lds, r + 3, B);
            uint32_t rpA = popc8(A), rpB = popc8(B);
            procC(A, B, 3, acc[0]);        /* (3, 3) -> j9  */
            proc0(A, B, rpA, rpB, acc[1]); /* (3, 0) -> j10 */
            procC(A, B, -3, acc[2]);       /* (3,-3) -> j11 */
        }
    }

    // butterfly over the wave's 64 rows (exact integer sums)
#pragma unroll
    for (int o = 0; o < 3; ++o)
#pragma unroll
        for (int q = 0; q < 3; ++q) {
            int v = (int)acc[o][q];
            for (int m = 32; m >= 1; m >>= 1) v += __shfl_xor(v, m, 64);
            acc[o][q] = (uint32_t)v;
        }
    if (lane == 0) {
        const int jt[4][3] = {{0, 4, 8}, {1, 2, 3}, {5, 6, 7}, {9, 10, 11}};
        uint32_t* pb = part + (size_t)blk * 36;
#pragma unroll
        for (int o = 0; o < 3; ++o)
#pragma unroll
            for (int q = 0; q < 3; ++q) pb[jt[wv][o] * 3 + q] = acc[o][q];
    }
    __syncthreads(); // all 36 partials of this block are in flight/written

    if (band != 0) {
        // worker: publish partials with release flag
        if (t == 0) {
            __threadfence();
            __hip_atomic_store(&flags[blk], MAGIC, __ATOMIC_RELEASE, __HIP_MEMORY_SCOPE_AGENT);
        }
        return;
    }

    // ---- finalizer (band 0): wait for bands 1..7, reduce, normalize, reset flags ----
    if (wv != 0) return;
    if (lane >= 1 && lane < NB) {
        while (__hip_atomic_load(&flags[blk + lane], __ATOMIC_ACQUIRE,
                                 __HIP_MEMORY_SCOPE_AGENT) != MAGIC)
            __builtin_amdgcn_s_sleep(2);
    }
    // wave reconverges only after every lane's spin completed
    __threadfence();

    if (lane < 12) {
        const int rtab[12] = {0, 1, 1, 1, 0, 2, 2, 2, 0, 3, 3, 3};
        const int ctab[12] = {1, 1, 0, -1, 2, 2, 0, -2, 3, 3, 0, -3};
        uint32_t oa = 0, ob = 0, on = 0;
        for (int k = 0; k < NB; ++k) {
            const uint32_t* p = part + (size_t)(blk + k) * 36 + lane * 3;
            oa += __hip_atomic_load(&p[0], __ATOMIC_RELAXED, __HIP_MEMORY_SCOPE_AGENT);
            ob += __hip_atomic_load(&p[1], __ATOMIC_RELAXED, __HIP_MEMORY_SCOPE_AGENT);
            on += __hip_atomic_load(&p[2], __ATOMIC_RELAXED, __HIP_MEMORY_SCOPE_AGENT);
        }
        int rr = rtab[lane];
        int sh = ctab[lane] < 0 ? -ctab[lane] : ctab[lane];
        float foa = (float)oa, fob = (float)ob, fon = (float)on;
        float Nwin = (float)((HH - rr) * (WW - sh));
        float e0 = 4.f * fon;                                  /* 2*M00 */
        float e1 = 2.f * (foa + fob) - 8.f * fon;              /* M01+M10 */
        float e3 = 2.f * Nwin - 4.f * (foa + fob) + 8.f * fon; /* 2*M11 */
        float inv = 1.0f / (2.f * Nwin - 4.f * fon);
        float4 o;
        o.x = e0 * inv; o.y = e1 * inv; o.z = e1 * inv; o.w = e3 * inv;
        *(float4*)(out + (size_t)b * 48 + lane * 4) = o;
    }
    // reset flags for the next call (steady-state invariant: flags == 0 on entry)
    if (lane >= 1 && lane < NB)
        __hip_atomic_store(&flags[blk + lane], 0u, __ATOMIC_RELEASE, __HIP_MEMORY_SCOPE_AGENT);
}

extern "C" void kernel_launch(void* const* d_in, const int* in_sizes, int n_in,
                              void* d_out, int out_size, void* d_ws, size_t ws_size,
                              hipStream_t stream) {
    const float* img = (const float*)d_in[0];
    float* out = (float*)d_out;
    uint32_t* part = (uint32_t*)d_ws;                    /* 1024*36 u32 = 144 KB */
    uint32_t* flags = (uint32_t*)d_ws + BATCH * NB * 36; /* 1024 u32 */
    (void)in_sizes; (void)n_in; (void)out_size; (void)ws_size;

    glcm_fused<<<dim3(BATCH * NB), dim3(256), 0, stream>>>(img, part, flags, out);
}

// Round 11
// 84.237 us; speedup vs baseline: 1.0177x; 1.0177x over previous
//
#include <hip/hip_runtime.h>
#include <stdint.h>

#define BATCH 128
#define HH 512
#define WW 512
#define BAND 64
#define NB (HH / BAND) /* 8 bands per batch */
#define HALO 3
#define PITCH 10 /* u64 per LDS row: 8 data + 2 pad */
#define MAGIC 0x5F3C9D21u

// ---- bit-domain helpers (layout: word w = h*4+k of a row; bit l <-> col 256h+4l+k) ----
__device__ __forceinline__ uint32_t popc8(const uint64_t* R) {
    uint32_t s = 0;
#pragma unroll
    for (int w = 0; w < 8; ++w) s += (uint32_t)__popcll(R[w]);
    return s;
}

// S(col p) = R(col p+sh), sh in 1..3 (compile-time).
__device__ __forceinline__ void shiftdn(const uint64_t* R, const int sh, uint64_t* S) {
#pragma unroll
    for (int t8 = 0; t8 < 2; ++t8)
#pragma unroll
        for (int k = 0; k < 4; ++k) {
            int kc = k + sh;
            if (kc < 4) {
                S[t8 * 4 + k] = R[t8 * 4 + kc];
            } else {
                uint64_t x = R[t8 * 4 + kc - 4] >> 1;
                if (t8 == 0) x |= R[4 + kc - 4] << 63;
                S[t8 * 4 + k] = x;
            }
        }
}

// Pair stats for column offset c != 0 (compile-time) between a-row A and b-row B.
__device__ __forceinline__ void procC(const uint64_t* A, const uint64_t* B, const int c,
                                      uint32_t* acc) {
    const int sh = c > 0 ? c : -c;
    uint64_t S[8];
    uint32_t oa = 0, ob = 0, on = 0;
    if (c > 0) {
        shiftdn(B, sh, S);
#pragma unroll
        for (int w = 0; w < 8; ++w) {
            uint64_t a = A[w];
            uint64_t am = ((w >> 2) == 1 && (w & 3) >= 4 - sh) ? (a & ~(1ull << 63)) : a;
            oa += (uint32_t)__popcll(am);
            ob += (uint32_t)__popcll(S[w]);
            on += (uint32_t)__popcll(a & S[w]);
        }
    } else {
        shiftdn(A, sh, S);
#pragma unroll
        for (int w = 0; w < 8; ++w) {
            uint64_t bb = B[w];
            uint64_t bm = ((w >> 2) == 1 && (w & 3) >= 4 - sh) ? (bb & ~(1ull << 63)) : bb;
            oa += (uint32_t)__popcll(S[w]);
            ob += (uint32_t)__popcll(bm);
            on += (uint32_t)__popcll(S[w] & bb);
        }
    }
    acc[0] += oa; acc[1] += ob; acc[2] += on;
}

__device__ __forceinline__ void proc0(const uint64_t* A, const uint64_t* B,
                                      uint32_t rpA, uint32_t rpB, uint32_t* acc) {
    uint32_t on = 0;
#pragma unroll
    for (int w = 0; w < 8; ++w) on += (uint32_t)__popcll(A[w] & B[w]);
    acc[0] += rpA; acc[1] += rpB; acc[2] += on;
}

__device__ __forceinline__ void loadrow(const uint64_t* lds, int y, uint64_t* R) {
#pragma unroll
    for (int i = 0; i < 4; ++i)
        *(ulonglong2*)&R[2 * i] = *(const ulonglong2*)&lds[y * PITCH + 2 * i];
}

// task id: row = id>>1, half = id&1
__device__ __forceinline__ float4 ldtask(const float* base, int y0, int id, int lane) {
    int row = id >> 1, half = id & 1;
    return *(const float4*)(base + (size_t)(y0 + row) * WW + half * 256 + lane * 4);
}

__device__ __forceinline__ void balstore(uint64_t* lds, int id, float4 v, int lane) {
    uint64_t m0 = __ballot(v.x < 0.f);
    uint64_t m1 = __ballot(v.y < 0.f);
    uint64_t m2 = __ballot(v.z < 0.f);
    uint64_t m3 = __ballot(v.w < 0.f);
    if (lane == 0) {
        int row = id >> 1, half = id & 1;
        uint64_t* p = &lds[row * PITCH + half * 4];
        ulonglong2 s0, s1;
        s0.x = m0; s0.y = m1; s1.x = m2; s1.y = m3;
        *(ulonglong2*)&p[0] = s0;
        *(ulonglong2*)&p[2] = s1;
    }
}

// Single fused kernel. Cross-block protocol = the round-7 HW-validated one:
//  worker: ordinary partial stores -> __syncthreads -> __threadfence (L2 writeback)
//          -> RELEASE-store MAGIC flag.
//  finalizer (band NB-1, dispatched last): ACQUIRE-load spin (each poll invalidates
//          local L2) with long s_sleep backoff -> __threadfence -> relaxed reads.
__global__ __launch_bounds__(256, 4) void glcm_fused(const float* __restrict__ img,
                                                     uint32_t* __restrict__ part,
                                                     uint32_t* __restrict__ flags,
                                                     float* __restrict__ out) {
    __shared__ uint64_t lds[(BAND + HALO) * PITCH];
    int blk = (int)blockIdx.x;
    int band = blk & (NB - 1);
    int b = blk >> 3;
    int y0 = band * BAND;
    int t = (int)threadIdx.x, lane = t & 63, wv = t >> 6;
    const float* base = img + (size_t)b * HH * WW;

    int nrows = min(BAND + HALO, HH - y0);
    int ntasks = nrows * 2; /* half-rows */

    // ---- staging: pipelined ballot-pack (tasks strided by 4 waves) ----
    int id = wv;
    for (; id + 12 < ntasks; id += 16) {
        float4 v0 = ldtask(base, y0, id, lane);
        float4 v1 = ldtask(base, y0, id + 4, lane);
        float4 v2 = ldtask(base, y0, id + 8, lane);
        float4 v3 = ldtask(base, y0, id + 12, lane);
        balstore(lds, id, v0, lane);
        balstore(lds, id + 4, v1, lane);
        balstore(lds, id + 8, v2, lane);
        balstore(lds, id + 12, v3, lane);
    }
    for (; id < ntasks; id += 4) {
        float4 v = ldtask(base, y0, id, lane);
        balstore(lds, id, v, lane);
    }
    __syncthreads();

    // ---- compute: wave wv = offset group, lane = a-row within band ----
    uint32_t acc[3][3];
#pragma unroll
    for (int o = 0; o < 3; ++o) { acc[o][0] = 0; acc[o][1] = 0; acc[o][2] = 0; }

    int r = lane;
    uint64_t A[8];
    loadrow(lds, r, A);

    if (wv == 0) {
        procC(A, A, 1, acc[0]); /* (0,1) -> j0 */
        procC(A, A, 2, acc[1]); /* (0,2) -> j4 */
        procC(A, A, 3, acc[2]); /* (0,3) -> j8 */
    } else if (wv == 1) {
        if (y0 + r + 1 < HH) {
            uint64_t B[8];
            loadrow(lds, r + 1, B);
            uint32_t rpA = popc8(A), rpB = popc8(B);
            procC(A, B, 1, acc[0]);        /* (1, 1) -> j1 */
            proc0(A, B, rpA, rpB, acc[1]); /* (1, 0) -> j2 */
            procC(A, B, -1, acc[2]);       /* (1,-1) -> j3 */
        }
    } else if (wv == 2) {
        if (y0 + r + 2 < HH) {
            uint64_t B[8];
            loadrow(lds, r + 2, B);
            uint32_t rpA = popc8(A), rpB = popc8(B);
            procC(A, B, 2, acc[0]);        /* (2, 2) -> j5 */
            proc0(A, B, rpA, rpB, acc[1]); /* (2, 0) -> j6 */
            procC(A, B, -2, acc[2]);       /* (2,-2) -> j7 */
        }
    } else {
        if (y0 + r + 3 < HH) {
            uint64_t B[8];
            loadrow(lds, r + 3, B);
            uint32_t rpA = popc8(A), rpB = popc8(B);
            procC(A, B, 3, acc[0]);        /* (3, 3) -> j9  */
            proc0(A, B, rpA, rpB, acc[1]); /* (3, 0) -> j10 */
            procC(A, B, -3, acc[2]);       /* (3,-3) -> j11 */
        }
    }

    // butterfly over the wave's 64 rows (exact integer sums)
#pragma unroll
    for (int o = 0; o < 3; ++o)
#pragma unroll
        for (int q = 0; q < 3; ++q) {
            int v = (int)acc[o][q];
            for (int m = 32; m >= 1; m >>= 1) v += __shfl_xor(v, m, 64);
            acc[o][q] = (uint32_t)v;
        }
    if (lane == 0) {
        const int jt[4][3] = {{0, 4, 8}, {1, 2, 3}, {5, 6, 7}, {9, 10, 11}};
        uint32_t* pb = part + (size_t)blk * 36;
#pragma unroll
        for (int o = 0; o < 3; ++o)
#pragma unroll
            for (int q = 0; q < 3; ++q) pb[jt[wv][o] * 3 + q] = acc[o][q];
    }
    __syncthreads(); // all 36 partials of this block written (program order)

    if (band != NB - 1) {
        // worker: flush partials to coherence point, then publish
        if (t == 0) {
            __threadfence();
            __hip_atomic_store(&flags[blk], MAGIC, __ATOMIC_RELEASE, __HIP_MEMORY_SCOPE_AGENT);
        }
        return;
    }

    // ---- finalizer (band NB-1, dispatched last): acquire-spin with long backoff ----
    if (wv != 0) return;
    int base_blk = blk - band; /* = b * NB */
    if (lane < NB - 1) {
        // first poll usually succeeds (siblings launched earlier); back off 4096 cyc
        while (__hip_atomic_load(&flags[base_blk + lane], __ATOMIC_ACQUIRE,
                                 __HIP_MEMORY_SCOPE_AGENT) != MAGIC)
            __builtin_amdgcn_s_sleep(64);
    }
    __threadfence(); // reconverged: all flags observed MAGIC

    if (lane < 12) {
        const int rtab[12] = {0, 1, 1, 1, 0, 2, 2, 2, 0, 3, 3, 3};
        const int ctab[12] = {1, 1, 0, -1, 2, 2, 0, -2, 3, 3, 0, -3};
        uint32_t oa = 0, ob = 0, on = 0;
        for (int k = 0; k < NB; ++k) {
            const uint32_t* p = part + (size_t)(base_blk + k) * 36 + lane * 3;
            oa += __hip_atomic_load(&p[0], __ATOMIC_RELAXED, __HIP_MEMORY_SCOPE_AGENT);
            ob += __hip_atomic_load(&p[1], __ATOMIC_RELAXED, __HIP_MEMORY_SCOPE_AGENT);
            on += __hip_atomic_load(&p[2], __ATOMIC_RELAXED, __HIP_MEMORY_SCOPE_AGENT);
        }
        int rr = rtab[lane];
        int sh = ctab[lane] < 0 ? -ctab[lane] : ctab[lane];
        float foa = (float)oa, fob = (float)ob, fon = (float)on;
        float Nwin = (float)((HH - rr) * (WW - sh));
        float e0 = 4.f * fon;                                  /* 2*M00 */
        float e1 = 2.f * (foa + fob) - 8.f * fon;              /* M01+M10 */
        float e3 = 2.f * Nwin - 4.f * (foa + fob) + 8.f * fon; /* 2*M11 */
        float inv = 1.0f / (2.f * Nwin - 4.f * fon);
        float4 o;
        o.x = e0 * inv; o.y = e1 * inv; o.z = e1 * inv; o.w = e3 * inv;
        *(float4*)(out + (size_t)b * 48 + lane * 4) = o;
    } else if (lane >= 12 && lane < 12 + NB - 1) {
        // reset sibling flags for the next call (steady-state: flags == 0 on entry)
        __hip_atomic_store(&flags[base_blk + (lane - 12)], 0u, __ATOMIC_RELEASE,
                           __HIP_MEMORY_SCOPE_AGENT);
    }
}

extern "C" void kernel_launch(void* const* d_in, const int* in_sizes, int n_in,
                              void* d_out, int out_size, void* d_ws, size_t ws_size,
                              hipStream_t stream) {
    const float* img = (const float*)d_in[0];
    float* out = (float*)d_out;
    uint32_t* part = (uint32_t*)d_ws;                    /* 1024*36 u32 = 144 KB */
    uint32_t* flags = (uint32_t*)d_ws + BATCH * NB * 36; /* 1024 u32 */
    (void)in_sizes; (void)n_in; (void)out_size; (void)ws_size;

    glcm_fused<<<dim3(BATCH * NB), dim3(256), 0, stream>>>(img, part, flags, out);
}

// Round 13
// 30.059 us; speedup vs baseline: 2.8520x; 2.8024x over previous
//
#include <hip/hip_runtime.h>
#include <stdint.h>

#define BATCH 128
#define HH 512
#define WW 512
#define BAND 64
#define NB (HH / BAND) /* 8 bands per batch */
#define HALO 3
#define PITCH 10 /* u64 per LDS row: 8 data + 2 pad */

typedef float f32x4 __attribute__((ext_vector_type(4)));

// ---- bit-domain helpers (layout: word w = h*4+k of a row; bit l <-> col 256h+4l+k) ----
__device__ __forceinline__ uint32_t popc8(const uint64_t* R) {
    uint32_t s = 0;
#pragma unroll
    for (int w = 0; w < 8; ++w) s += (uint32_t)__popcll(R[w]);
    return s;
}

// S(col p) = R(col p+sh), sh in 1..3 (compile-time).
__device__ __forceinline__ void shiftdn(const uint64_t* R, const int sh, uint64_t* S) {
#pragma unroll
    for (int t8 = 0; t8 < 2; ++t8)
#pragma unroll
        for (int k = 0; k < 4; ++k) {
            int kc = k + sh;
            if (kc < 4) {
                S[t8 * 4 + k] = R[t8 * 4 + kc];
            } else {
                uint64_t x = R[t8 * 4 + kc - 4] >> 1;
                if (t8 == 0) x |= R[4 + kc - 4] << 63;
                S[t8 * 4 + k] = x;
            }
        }
}

// Pair stats for column offset c != 0 (compile-time) between a-row A and b-row B.
__device__ __forceinline__ void procC(const uint64_t* A, const uint64_t* B, const int c,
                                      uint32_t* acc) {
    const int sh = c > 0 ? c : -c;
    uint64_t S[8];
    uint32_t oa = 0, ob = 0, on = 0;
    if (c > 0) {
        shiftdn(B, sh, S);
#pragma unroll
        for (int w = 0; w < 8; ++w) {
            uint64_t a = A[w];
            uint64_t am = ((w >> 2) == 1 && (w & 3) >= 4 - sh) ? (a & ~(1ull << 63)) : a;
            oa += (uint32_t)__popcll(am);
            ob += (uint32_t)__popcll(S[w]);
            on += (uint32_t)__popcll(a & S[w]);
        }
    } else {
        shiftdn(A, sh, S);
#pragma unroll
        for (int w = 0; w < 8; ++w) {
            uint64_t bb = B[w];
            uint64_t bm = ((w >> 2) == 1 && (w & 3) >= 4 - sh) ? (bb & ~(1ull << 63)) : bb;
            oa += (uint32_t)__popcll(S[w]);
            ob += (uint32_t)__popcll(bm);
            on += (uint32_t)__popcll(S[w] & bb);
        }
    }
    acc[0] += oa; acc[1] += ob; acc[2] += on;
}

__device__ __forceinline__ void proc0(const uint64_t* A, const uint64_t* B,
                                      uint32_t rpA, uint32_t rpB, uint32_t* acc) {
    uint32_t on = 0;
#pragma unroll
    for (int w = 0; w < 8; ++w) on += (uint32_t)__popcll(A[w] & B[w]);
    acc[0] += rpA; acc[1] += rpB; acc[2] += on;
}

__device__ __forceinline__ void loadrow(const uint64_t* lds, int y, uint64_t* R) {
#pragma unroll
    for (int i = 0; i < 4; ++i)
        *(ulonglong2*)&R[2 * i] = *(const ulonglong2*)&lds[y * PITCH + 2 * i];
}

// task id: row = id>>1, half = id&1. Non-temporal: image is read exactly once.
__device__ __forceinline__ f32x4 ldtask(const float* base, int y0, int id, int lane) {
    int row = id >> 1, half = id & 1;
    return __builtin_nontemporal_load(
        (const f32x4*)(base + (size_t)(y0 + row) * WW + half * 256 + lane * 4));
}

__device__ __forceinline__ void balstore(uint64_t* lds, int id, f32x4 v, int lane) {
    uint64_t m0 = __ballot(v.x < 0.f);
    uint64_t m1 = __ballot(v.y < 0.f);
    uint64_t m2 = __ballot(v.z < 0.f);
    uint64_t m3 = __ballot(v.w < 0.f);
    if (lane == 0) {
        int row = id >> 1, half = id & 1;
        uint64_t* p = &lds[row * PITCH + half * 4];
        ulonglong2 s0, s1;
        s0.x = m0; s0.y = m1; s1.x = m2; s1.y = m3;
        *(ulonglong2*)&p[0] = s0;
        *(ulonglong2*)&p[2] = s1;
    }
}

// Kernel 1: ballot-pack band (+halo) into LDS, then popcount all 12 offsets.
// part[blk*36 + j*3 + q], j = offset index 0..11, q = {oa, ob, on}.
__global__ __launch_bounds__(256) void glcm_fused(const float* __restrict__ img,
                                                  uint32_t* __restrict__ part) {
    __shared__ uint64_t lds[(BAND + HALO) * PITCH];
    int blk = (int)blockIdx.x;
    int band = blk & (NB - 1);
    int b = blk >> 3;
    int y0 = band * BAND;
    int t = (int)threadIdx.x, lane = t & 63, wv = t >> 6;
    const float* base = img + (size_t)b * HH * WW;

    int nrows = min(BAND + HALO, HH - y0);
    int ntasks = nrows * 2; /* half-rows */

    // ---- staging: 2-deep pipelined ballot-pack (tasks strided by 4 waves) ----
    int id = wv;
    while (id + 4 < ntasks) {
        f32x4 v0 = ldtask(base, y0, id, lane);
        f32x4 v1 = ldtask(base, y0, id + 4, lane);
        balstore(lds, id, v0, lane);
        balstore(lds, id + 4, v1, lane);
        id += 8;
    }
    if (id < ntasks) {
        f32x4 v = ldtask(base, y0, id, lane);
        balstore(lds, id, v, lane);
    }
    __syncthreads();

    // ---- compute: wave wv = offset group, lane = a-row within band ----
    uint32_t acc[3][3];
#pragma unroll
    for (int o = 0; o < 3; ++o) { acc[o][0] = 0; acc[o][1] = 0; acc[o][2] = 0; }

    int r = lane;
    uint64_t A[8];
    loadrow(lds, r, A);

    if (wv == 0) {
        procC(A, A, 1, acc[0]); /* (0,1) -> j0 */
        procC(A, A, 2, acc[1]); /* (0,2) -> j4 */
        procC(A, A, 3, acc[2]); /* (0,3) -> j8 */
    } else if (wv == 1) {
        if (y0 + r + 1 < HH) {
            uint64_t B[8];
            loadrow(lds, r + 1, B);
            uint32_t rpA = popc8(A), rpB = popc8(B);
            procC(A, B, 1, acc[0]);        /* (1, 1) -> j1 */
            proc0(A, B, rpA, rpB, acc[1]); /* (1, 0) -> j2 */
            procC(A, B, -1, acc[2]);       /* (1,-1) -> j3 */
        }
    } else if (wv == 2) {
        if (y0 + r + 2 < HH) {
            uint64_t B[8];
            loadrow(lds, r + 2, B);
            uint32_t rpA = popc8(A), rpB = popc8(B);
            procC(A, B, 2, acc[0]);        /* (2, 2) -> j5 */
            proc0(A, B, rpA, rpB, acc[1]); /* (2, 0) -> j6 */
            procC(A, B, -2, acc[2]);       /* (2,-2) -> j7 */
        }
    } else {
        if (y0 + r + 3 < HH) {
            uint64_t B[8];
            loadrow(lds, r + 3, B);
            uint32_t rpA = popc8(A), rpB = popc8(B);
            procC(A, B, 3, acc[0]);        /* (3, 3) -> j9  */
            proc0(A, B, rpA, rpB, acc[1]); /* (3, 0) -> j10 */
            procC(A, B, -3, acc[2]);       /* (3,-3) -> j11 */
        }
    }

    // butterfly over the wave's 64 rows (exact integer sums)
#pragma unroll
    for (int o = 0; o < 3; ++o)
#pragma unroll
        for (int q = 0; q < 3; ++q) {
            int v = (int)acc[o][q];
            for (int m = 32; m >= 1; m >>= 1) v += __shfl_xor(v, m, 64);
            acc[o][q] = (uint32_t)v;
        }
    if (lane == 0) {
        const int jt[4][3] = {{0, 4, 8}, {1, 2, 3}, {5, 6, 7}, {9, 10, 11}};
        uint32_t* pb = part + (size_t)blk * 36;
#pragma unroll
        for (int o = 0; o < 3; ++o)
#pragma unroll
            for (int q = 0; q < 3; ++q)
                __builtin_nontemporal_store(acc[o][q], &pb[jt[wv][o] * 3 + q]);
    }
}

// Kernel 2: per batch, sum 8 band-partials, normalize, write 48 outputs.
__global__ __launch_bounds__(64) void glcm_final(const uint32_t* __restrict__ part,
                                                 float* __restrict__ out) {
    __shared__ uint32_t sums[36];
    int b = (int)blockIdx.x;
    int t = (int)threadIdx.x;
    if (t < 36) {
        uint32_t s = 0;
        const uint32_t* p = part + (size_t)b * NB * 36 + t;
#pragma unroll
        for (int k = 0; k < NB; ++k) s += p[k * 36];
        sums[t] = s;
    }
    __syncthreads();
    if (t < 12) {
        const int rtab[12] = {0, 1, 1, 1, 0, 2, 2, 2, 0, 3, 3, 3};
        const int ctab[12] = {1, 1, 0, -1, 2, 2, 0, -2, 3, 3, 0, -3};
        int r = rtab[t];
        int sh = ctab[t] < 0 ? -ctab[t] : ctab[t];
        float foa = (float)sums[t * 3 + 0];
        float fob = (float)sums[t * 3 + 1];
        float fon = (float)sums[t * 3 + 2];
        float Nwin = (float)((HH - r) * (WW - sh));
        float e0 = 4.f * fon;                                  /* 2*M00 */
        float e1 = 2.f * (foa + fob) - 8.f * fon;              /* M01+M10 */
        float e3 = 2.f * Nwin - 4.f * (foa + fob) + 8.f * fon; /* 2*M11 */
        float inv = 1.0f / (2.f * Nwin - 4.f * fon);
        float4 o;
        o.x = e0 * inv; o.y = e1 * inv; o.z = e1 * inv; o.w = e3 * inv;
        *(float4*)(out + (size_t)b * 48 + t * 4) = o;
    }
}

extern "C" void kernel_launch(void* const* d_in, const int* in_sizes, int n_in,
                              void* d_out, int out_size, void* d_ws, size_t ws_size,
                              hipStream_t stream) {
    const float* img = (const float*)d_in[0];
    float* out = (float*)d_out;
    uint32_t* part = (uint32_t*)d_ws; /* BATCH*NB*36 u32 = 144 KB */
    (void)in_sizes; (void)n_in; (void)out_size; (void)ws_size;

    glcm_fused<<<dim3(BATCH * NB), dim3(256), 0, stream>>>(img, part);
    glcm_final<<<dim3(BATCH), dim3(64), 0, stream>>>(part, out);
}

// Round 14
// 29.644 us; speedup vs baseline: 2.8919x; 1.0140x over previous
//
#include <hip/hip_runtime.h>
#include <stdint.h>

#define BATCH 128
#define HH 512
#define WW 512
#define BAND 128
#define NB (HH / BAND) /* 4 bands per batch */
#define HALO 3
#define PITCH 10 /* u64 per LDS row: 8 data + 2 pad */

typedef float f32x4 __attribute__((ext_vector_type(4)));

// ---- bit-domain helpers (layout: word w = h*4+k of a row; bit l <-> col 256h+4l+k) ----
__device__ __forceinline__ uint32_t popc8(const uint64_t* R) {
    uint32_t s = 0;
#pragma unroll
    for (int w = 0; w < 8; ++w) s += (uint32_t)__popcll(R[w]);
    return s;
}

// S(col p) = R(col p+sh), sh in 1..3 (compile-time).
__device__ __forceinline__ void shiftdn(const uint64_t* R, const int sh, uint64_t* S) {
#pragma unroll
    for (int t8 = 0; t8 < 2; ++t8)
#pragma unroll
        for (int k = 0; k < 4; ++k) {
            int kc = k + sh;
            if (kc < 4) {
                S[t8 * 4 + k] = R[t8 * 4 + kc];
            } else {
                uint64_t x = R[t8 * 4 + kc - 4] >> 1;
                if (t8 == 0) x |= R[4 + kc - 4] << 63;
                S[t8 * 4 + k] = x;
            }
        }
}

// Pair stats for column offset c != 0 (compile-time) between a-row A and b-row B.
__device__ __forceinline__ void procC(const uint64_t* A, const uint64_t* B, const int c,
                                      uint32_t* acc) {
    const int sh = c > 0 ? c : -c;
    uint64_t S[8];
    uint32_t oa = 0, ob = 0, on = 0;
    if (c > 0) {
        shiftdn(B, sh, S);
#pragma unroll
        for (int w = 0; w < 8; ++w) {
            uint64_t a = A[w];
            uint64_t am = ((w >> 2) == 1 && (w & 3) >= 4 - sh) ? (a & ~(1ull << 63)) : a;
            oa += (uint32_t)__popcll(am);
            ob += (uint32_t)__popcll(S[w]);
            on += (uint32_t)__popcll(a & S[w]);
        }
    } else {
        shiftdn(A, sh, S);
#pragma unroll
        for (int w = 0; w < 8; ++w) {
            uint64_t bb = B[w];
            uint64_t bm = ((w >> 2) == 1 && (w & 3) >= 4 - sh) ? (bb & ~(1ull << 63)) : bb;
            oa += (uint32_t)__popcll(S[w]);
            ob += (uint32_t)__popcll(bm);
            on += (uint32_t)__popcll(S[w] & bb);
        }
    }
    acc[0] += oa; acc[1] += ob; acc[2] += on;
}

__device__ __forceinline__ void proc0(const uint64_t* A, const uint64_t* B,
                                      uint32_t rpA, uint32_t rpB, uint32_t* acc) {
    uint32_t on = 0;
#pragma unroll
    for (int w = 0; w < 8; ++w) on += (uint32_t)__popcll(A[w] & B[w]);
    acc[0] += rpA; acc[1] += rpB; acc[2] += on;
}

__device__ __forceinline__ void loadrow(const uint64_t* lds, int y, uint64_t* R) {
#pragma unroll
    for (int i = 0; i < 4; ++i)
        *(ulonglong2*)&R[2 * i] = *(const ulonglong2*)&lds[y * PITCH + 2 * i];
}

// task id: row = id>>1, half = id&1. Non-temporal: image is read exactly once.
__device__ __forceinline__ f32x4 ldtask(const float* base, int y0, int id, int lane) {
    int row = id >> 1, half = id & 1;
    return __builtin_nontemporal_load(
        (const f32x4*)(base + (size_t)(y0 + row) * WW + half * 256 + lane * 4));
}

__device__ __forceinline__ void balstore(uint64_t* lds, int id, f32x4 v, int lane) {
    uint64_t m0 = __ballot(v.x < 0.f);
    uint64_t m1 = __ballot(v.y < 0.f);
    uint64_t m2 = __ballot(v.z < 0.f);
    uint64_t m3 = __ballot(v.w < 0.f);
    if (lane == 0) {
        int row = id >> 1, half = id & 1;
        uint64_t* p = &lds[row * PITCH + half * 4];
        ulonglong2 s0, s1;
        s0.x = m0; s0.y = m1; s1.x = m2; s1.y = m3;
        *(ulonglong2*)&p[0] = s0;
        *(ulonglong2*)&p[2] = s1;
    }
}

// Kernel 1: ballot-pack 128-row band (+3 halo) into LDS, popcount all 12 offsets.
// 8 waves: wave w = offset-group (w&3) x row-half (w>>2); rows (w>>2)*64 + lane.
// part[blk*72 + (w>>2)*36 + j*3 + q].
__global__ __launch_bounds__(512) void glcm_main(const float* __restrict__ img,
                                                 uint32_t* __restrict__ part) {
    __shared__ uint64_t lds[(BAND + HALO) * PITCH]; /* 10480 B */
    int blk = (int)blockIdx.x;
    int band = blk & (NB - 1);
    int b = blk >> 2;
    int y0 = band * BAND;
    int t = (int)threadIdx.x, lane = t & 63, wv = t >> 6;
    const float* base = img + (size_t)b * HH * WW;

    int nrows = min(BAND + HALO, HH - y0);
    int ntasks = nrows * 2; /* half-rows */

    // ---- staging: 2-deep pipelined ballot-pack (tasks strided by 8 waves) ----
    int id = wv;
    for (; id + 8 < ntasks; id += 16) {
        f32x4 v0 = ldtask(base, y0, id, lane);
        f32x4 v1 = ldtask(base, y0, id + 8, lane);
        balstore(lds, id, v0, lane);
        balstore(lds, id + 8, v1, lane);
    }
    for (; id < ntasks; id += 8) {
        f32x4 v = ldtask(base, y0, id, lane);
        balstore(lds, id, v, lane);
    }
    __syncthreads();

    // ---- compute: group g = wv&3, row r = (wv>>2)*64 + lane ----
    uint32_t acc[3][3];
#pragma unroll
    for (int o = 0; o < 3; ++o) { acc[o][0] = 0; acc[o][1] = 0; acc[o][2] = 0; }

    int g = wv & 3;
    int hb = wv >> 2;
    int r = hb * 64 + lane;
    uint64_t A[8];
    loadrow(lds, r, A);

    if (g == 0) {
        procC(A, A, 1, acc[0]); /* (0,1) -> j0 */
        procC(A, A, 2, acc[1]); /* (0,2) -> j4 */
        procC(A, A, 3, acc[2]); /* (0,3) -> j8 */
    } else if (g == 1) {
        if (y0 + r + 1 < HH) {
            uint64_t B[8];
            loadrow(lds, r + 1, B);
            uint32_t rpA = popc8(A), rpB = popc8(B);
            procC(A, B, 1, acc[0]);        /* (1, 1) -> j1 */
            proc0(A, B, rpA, rpB, acc[1]); /* (1, 0) -> j2 */
            procC(A, B, -1, acc[2]);       /* (1,-1) -> j3 */
        }
    } else if (g == 2) {
        if (y0 + r + 2 < HH) {
            uint64_t B[8];
            loadrow(lds, r + 2, B);
            uint32_t rpA = popc8(A), rpB = popc8(B);
            procC(A, B, 2, acc[0]);        /* (2, 2) -> j5 */
            proc0(A, B, rpA, rpB, acc[1]); /* (2, 0) -> j6 */
            procC(A, B, -2, acc[2]);       /* (2,-2) -> j7 */
        }
    } else {
        if (y0 + r + 3 < HH) {
            uint64_t B[8];
            loadrow(lds, r + 3, B);
            uint32_t rpA = popc8(A), rpB = popc8(B);
            procC(A, B, 3, acc[0]);        /* (3, 3) -> j9  */
            proc0(A, B, rpA, rpB, acc[1]); /* (3, 0) -> j10 */
            procC(A, B, -3, acc[2]);       /* (3,-3) -> j11 */
        }
    }

    // butterfly over the wave's 64 rows (exact integer sums)
#pragma unroll
    for (int o = 0; o < 3; ++o)
#pragma unroll
        for (int q = 0; q < 3; ++q) {
            int v = (int)acc[o][q];
            for (int m = 32; m >= 1; m >>= 1) v += __shfl_xor(v, m, 64);
            acc[o][q] = (uint32_t)v;
        }
    if (lane == 0) {
        const int jt[4][3] = {{0, 4, 8}, {1, 2, 3}, {5, 6, 7}, {9, 10, 11}};
        uint32_t* pb = part + (size_t)blk * 72 + hb * 36;
#pragma unroll
        for (int o = 0; o < 3; ++o)
#pragma unroll
            for (int q = 0; q < 3; ++q)
                __builtin_nontemporal_store(acc[o][q], &pb[jt[g][o] * 3 + q]);
    }
}

// Kernel 2: per batch, sum 8 chunk-partials (4 bands x 2 halves), normalize, write 48.
__global__ __launch_bounds__(64) void glcm_final(const uint32_t* __restrict__ part,
                                                 float* __restrict__ out) {
    __shared__ uint32_t sums[36];
    int b = (int)blockIdx.x;
    int t = (int)threadIdx.x;
    if (t < 36) {
        uint32_t s = 0;
        const uint32_t* p = part + (size_t)b * (NB * 72) + t;
#pragma unroll
        for (int m = 0; m < NB * 2; ++m) s += p[m * 36];
        sums[t] = s;
    }
    __syncthreads();
    if (t < 12) {
        const int rtab[12] = {0, 1, 1, 1, 0, 2, 2, 2, 0, 3, 3, 3};
        const int ctab[12] = {1, 1, 0, -1, 2, 2, 0, -2, 3, 3, 0, -3};
        int r = rtab[t];
        int sh = ctab[t] < 0 ? -ctab[t] : ctab[t];
        float foa = (float)sums[t * 3 + 0];
        float fob = (float)sums[t * 3 + 1];
        float fon = (float)sums[t * 3 + 2];
        float Nwin = (float)((HH - r) * (WW - sh));
        float e0 = 4.f * fon;                                  /* 2*M00 */
        float e1 = 2.f * (foa + fob) - 8.f * fon;              /* M01+M10 */
        float e3 = 2.f * Nwin - 4.f * (foa + fob) + 8.f * fon; /* 2*M11 */
        float inv = 1.0f / (2.f * Nwin - 4.f * fon);
        float4 o;
        o.x = e0 * inv; o.y = e1 * inv; o.z = e1 * inv; o.w = e3 * inv;
        *(float4*)(out + (size_t)b * 48 + t * 4) = o;
    }
}

extern "C" void kernel_launch(void* const* d_in, const int* in_sizes, int n_in,
                              void* d_out, int out_size, void* d_ws, size_t ws_size,
                              hipStream_t stream) {
    const float* img = (const float*)d_in[0];
    float* out = (float*)d_out;
    uint32_t* part = (uint32_t*)d_ws; /* BATCH*NB*72 u32 = 144 KB */
    (void)in_sizes; (void)n_in; (void)out_size; (void)ws_size;

    glcm_main<<<dim3(BATCH * NB), dim3(512), 0, stream>>>(img, part);
    glcm_final<<<dim3(BATCH), dim3(64), 0, stream>>>(part, out);
}